// Round 1
// baseline (1517.143 us; speedup 1.0000x reference)
//
#include <hip/hip_runtime.h>
#include <math.h>

typedef unsigned short u16;
typedef short v8s __attribute__((ext_vector_type(8)));
typedef float v4f __attribute__((ext_vector_type(4)));

#define MTOT 4096   // BS*SEQ = 32*128

// ---------- helpers ----------
__device__ __forceinline__ u16 f2bf(float f) {
  unsigned int u = __float_as_uint(f);
  u += 0x7fffu + ((u >> 16) & 1u);   // RNE
  return (u16)(u >> 16);
}

__device__ __forceinline__ v4f mfma16(v8s a, v8s b, v4f c) {
  return __builtin_amdgcn_mfma_f32_16x16x32_bf16(a, b, c, 0, 0, 0);
}

__device__ __forceinline__ void gl_lds16(const u16* g, u16* l) {
  __builtin_amdgcn_global_load_lds(
      (const __attribute__((address_space(1))) void*)g,
      (__attribute__((address_space(3))) void*)l, 16, 0, 0);
}

// theta = 3*pi/4 * ((y+x) mod 8)
__constant__ float c_ct[8] = {1.f, -0.70710678118654752f, 0.f, 0.70710678118654752f,
                              -1.f, 0.70710678118654752f, 0.f, -0.70710678118654752f};
__constant__ float c_st[8] = {0.f, 0.70710678118654752f, -1.f, 0.70710678118654752f,
                              0.f, -0.70710678118654752f, 1.f, -0.70710678118654752f};

// ---------- weight transpose + bf16 convert: src (L,K,N) f32 -> dst rows (rowOff+n) length K bf16 ----------
__global__ __launch_bounds__(256) void transpose_bf16_kernel(
    const float* __restrict__ src, u16* __restrict__ dst,
    int K, int N, size_t srcLS, size_t dstLS, int rowOff)
{
  int l = blockIdx.z;
  int n0 = blockIdx.x * 32, k0 = blockIdx.y * 32;
  __shared__ float tile[32][33];
  int tx = threadIdx.x & 31, ty = threadIdx.x >> 5;   // 32 x 8
  const float* s = src + (size_t)l * srcLS;
#pragma unroll
  for (int rr = 0; rr < 4; ++rr) {
    int k = k0 + ty + rr * 8;
    tile[ty + rr * 8][tx] = s[(size_t)k * N + n0 + tx];
  }
  __syncthreads();
  u16* dp = dst + (size_t)l * dstLS;
#pragma unroll
  for (int rr = 0; rr < 4; ++rr) {
    int n = n0 + ty + rr * 8;
    dp[(size_t)(rowOff + n) * K + k0 + tx] = f2bf(tile[tx][ty + rr * 8]);
  }
}

// ---------- concat qkv bias ----------
__global__ __launch_bounds__(256) void qkvbias_kernel(
    const float* __restrict__ bq, const float* __restrict__ bk,
    const float* __restrict__ bv, float* __restrict__ qb)
{
  int l = blockIdx.x;
  for (int j = threadIdx.x; j < 1536; j += 256) {
    float v = (j < 512) ? bq[l * 512 + j] : (j < 1024) ? bk[l * 512 + j - 512] : bv[l * 512 + j - 1024];
    qb[l * 1536 + j] = v;
  }
}

// ---------- 4x4 avg pool: out layout [t][b][c][hw], hw = y*8+x ----------
__global__ __launch_bounds__(256) void pool_kernel(
    const float* __restrict__ rgb, const float* __restrict__ ir, float* __restrict__ pool)
{
  int idx = blockIdx.x * 4 + (threadIdx.x >> 6);   // over 2*32*512
  int i = threadIdx.x & 63;
  int y = i >> 3, xcol = i & 7;
  int timg = idx >> 14;
  int rem = idx & 16383;                            // b*512+c
  const float* src = (timg ? ir : rgb) + (size_t)rem * 1024;
  float s = 0.f;
#pragma unroll
  for (int r = 0; r < 4; ++r) {
    float4 v = *(const float4*)(src + (y * 4 + r) * 32 + xcol * 4);
    s += v.x + v.y + v.z + v.w;
  }
  pool[(size_t)idx * 64 + i] = s * 0.0625f;
}

// ---------- highpass(+analytic DFT bin removal) + conv1(8<-512) + sigmoid -> M masks ----------
__global__ __launch_bounds__(256) void convm_kernel(
    const float* __restrict__ pool, const float* __restrict__ conv1_w,
    float* __restrict__ Mplain, float* __restrict__ Mhp)
{
  int bid = blockIdx.x;
  int kind, timg, b;
  if (bid < 64) { kind = 0; timg = bid >> 5; b = bid & 31; }
  else { int y = bid - 64; kind = 1; timg = y >> 2; b = y & 3; }
  int t = threadIdx.x, hw = t & 63, cg = t >> 6;
  int yy = hw >> 3, xx = hw & 7;
  int sd = (yy + xx) & 7;
  float ct = c_ct[sd], st = c_st[sd];
  float acc[8] = {0.f,0.f,0.f,0.f,0.f,0.f,0.f,0.f};
  const float* pbase = pool + ((size_t)(timg * 32 + b) * 512) * 64;
  for (int c = cg; c < 512; c += 4) {
    float p = pbase[c * 64 + hw];
    float val = p;
    if (kind == 1) {
      float C = p * ct, S = p * st;
#pragma unroll
      for (int d = 1; d < 64; d <<= 1) { C += __shfl_xor(C, d, 64); S += __shfl_xor(S, d, 64); }
      float hp = p - (C * ct + S * st) * (1.0f / 64.0f);
      val = hp * p;
    }
#pragma unroll
    for (int o = 0; o < 8; ++o) acc[o] += conv1_w[o * 512 + c] * val;
  }
  __shared__ float red[4][8][64];
#pragma unroll
  for (int o = 0; o < 8; ++o) red[cg][o][hw] = acc[o];
  __syncthreads();
  if (cg == 0) {
#pragma unroll
    for (int o = 0; o < 8; ++o) {
      float s = red[0][o][hw] + red[1][o][hw] + red[2][o][hw] + red[3][o][hw];
      float m = 1.0f / (1.0f + expf(-s));
      if (kind == 0) Mplain[((size_t)(timg * 32 + b) * 8 + o) * 64 + hw] = m;
      else           Mhp[((size_t)(timg * 4 + b) * 8 + o) * 64 + hw] = m;
    }
  }
}

// ---------- patten_loss ----------
__global__ __launch_bounds__(256) void loss_kernel(
    const float* __restrict__ Mplain, const float* __restrict__ Mhp, float* __restrict__ out)
{
  int t = threadIdx.x, col = t & 63, rg = t >> 6;
  float sp = 0.f, sq = 0.f;
  for (int r = rg; r < 576; r += 4) {
    const float* rowp = (r < 512) ? (Mplain + (size_t)r * 64) : (Mhp + (size_t)(r - 512) * 64);
    float v = rowp[col];
    sp += v; sq += v * v;
  }
  __shared__ float scol[4][64], ssq[4][64];
  scol[rg][col] = sp; ssq[rg][col] = sq;
  __syncthreads();
  if (t < 64) {
    float s = scol[0][t] + scol[1][t] + scol[2][t] + scol[3][t];
    float q = ssq[0][t] + ssq[1][t] + ssq[2][t] + ssq[3][t];
    float ds = s * s;
#pragma unroll
    for (int d = 1; d < 64; d <<= 1) { ds += __shfl_xor(ds, d, 64); q += __shfl_xor(q, d, 64); }
    if (t == 0) *out = (ds - q) * 0.5f / (576.0f * 575.0f);
  }
}

// ---------- token build: x[b,s,d] = pos_emb[s,d] + (conv2(M))[b,d,hw] * p[t][b][d][hw] ----------
__global__ __launch_bounds__(256) void token_kernel(
    const float* __restrict__ pos_emb, const float* __restrict__ conv2_w,
    const float* __restrict__ Mplain, const float* __restrict__ pool, float* __restrict__ x)
{
  int bs_idx = blockIdx.x;           // b*128+s
  int b = bs_idx >> 7, s = bs_idx & 127;
  int timg = s >> 6, hw = s & 63;
  __shared__ float Ms[8];
  if (threadIdx.x < 8)
    Ms[threadIdx.x] = Mplain[((size_t)(timg * 32 + b) * 8 + threadIdx.x) * 64 + hw];
  __syncthreads();
#pragma unroll
  for (int i = 0; i < 2; ++i) {
    int d = threadIdx.x + i * 256;
    float acc = 0.f;
#pragma unroll
    for (int o = 0; o < 8; ++o) acc += conv2_w[d * 8 + o] * Ms[o];
    float p = pool[(((size_t)timg * 32 + b) * 512 + d) * 64 + hw];
    x[(size_t)bs_idx * 512 + d] = pos_emb[s * 512 + d] + acc * p;
  }
}

// ---------- LayerNorm over 512; out bf16 or f32 ----------
template<int OBF>
__global__ __launch_bounds__(256) void ln_kernel(
    const float* __restrict__ xin, const float* __restrict__ w,
    const float* __restrict__ bb, void* __restrict__ out)
{
  int row = blockIdx.x, t = threadIdx.x;
  float2 v = ((const float2*)(xin + (size_t)row * 512))[t];
  float s = v.x + v.y, q = v.x * v.x + v.y * v.y;
#pragma unroll
  for (int d = 1; d < 64; d <<= 1) { s += __shfl_xor(s, d, 64); q += __shfl_xor(q, d, 64); }
  __shared__ float ps[4], pq[4];
  int wv = t >> 6;
  if ((t & 63) == 0) { ps[wv] = s; pq[wv] = q; }
  __syncthreads();
  float S = ps[0] + ps[1] + ps[2] + ps[3];
  float Q = pq[0] + pq[1] + pq[2] + pq[3];
  float mean = S * (1.0f / 512.0f);
  float var = Q * (1.0f / 512.0f) - mean * mean;
  float rstd = rsqrtf(var + 1e-5f);
  float o0 = (v.x - mean) * rstd * w[t * 2] + bb[t * 2];
  float o1 = (v.y - mean) * rstd * w[t * 2 + 1] + bb[t * 2 + 1];
  if (OBF) { u16* o = (u16*)out + (size_t)row * 512; o[t * 2] = f2bf(o0); o[t * 2 + 1] = f2bf(o1); }
  else     { float* o = (float*)out + (size_t)row * 512; o[t * 2] = o0; o[t * 2 + 1] = o1; }
}

// ---------- GEMM: C(M x N) = A(M x K, bf16) * BT(N x K, bf16)^T + bias [+gelu] [+resid f32] ----------
// tile 128x128, BK=32, 256 thr (4 waves, each 64x64 = 4x4 16x16 tiles), m97 structure
template<int ACT, int RESID, int OBF>
__global__ __launch_bounds__(256) void gemm_bt(
    const u16* __restrict__ A, const u16* __restrict__ BT,
    const float* __restrict__ bias, const float* __restrict__ resid,
    void* __restrict__ Cout, int N, int K)
{
  __shared__ u16 As[128 * 32];
  __shared__ u16 Bs[128 * 32];
  const int m0 = blockIdx.y * 128, n0 = blockIdx.x * 128;
  const int t = threadIdx.x, lane = t & 63, w = t >> 6;
  const int lr = lane & 15, lq = lane >> 4;
  const int wm = (w & 1) * 64, wn = (w >> 1) * 64;
  v4f acc[4][4];
  const v4f vzero = {0.f, 0.f, 0.f, 0.f};
#pragma unroll
  for (int mt = 0; mt < 4; ++mt)
#pragma unroll
    for (int nt = 0; nt < 4; ++nt) acc[mt][nt] = vzero;

  for (int kk = 0; kk < K; kk += 32) {
    __syncthreads();
    {
      int r0 = t >> 2, c0 = (t & 3) << 3;
      gl_lds16(A  + (size_t)(m0 + r0) * K + kk + c0, As + (size_t)(w * 64) * 8);
      gl_lds16(BT + (size_t)(n0 + r0) * K + kk + c0, Bs + (size_t)(w * 64) * 8);
      int ch = 256 + t;
      int r1 = ch >> 2, c1 = (ch & 3) << 3;
      gl_lds16(A  + (size_t)(m0 + r1) * K + kk + c1, As + (size_t)(256 + w * 64) * 8);
      gl_lds16(BT + (size_t)(n0 + r1) * K + kk + c1, Bs + (size_t)(256 + w * 64) * 8);
    }
    __syncthreads();
    v8s a[4], b[4];
#pragma unroll
    for (int mt = 0; mt < 4; ++mt)
      a[mt] = *(const v8s*)(As + (wm + mt * 16 + lr) * 32 + lq * 8);
#pragma unroll
    for (int nt = 0; nt < 4; ++nt)
      b[nt] = *(const v8s*)(Bs + (wn + nt * 16 + lr) * 32 + lq * 8);
#pragma unroll
    for (int mt = 0; mt < 4; ++mt)
#pragma unroll
      for (int nt = 0; nt < 4; ++nt)
        acc[mt][nt] = mfma16(a[mt], b[nt], acc[mt][nt]);
  }

#pragma unroll
  for (int mt = 0; mt < 4; ++mt)
#pragma unroll
    for (int nt = 0; nt < 4; ++nt) {
      int col = n0 + wn + nt * 16 + lr;
      float bsv = bias[col];
#pragma unroll
      for (int r = 0; r < 4; ++r) {
        int row = m0 + wm + mt * 16 + lq * 4 + r;
        float v = acc[mt][nt][r] + bsv;
        if (ACT == 1) v = 0.5f * v * (1.0f + erff(v * 0.70710678118654752f));
        if (RESID) v += resid[(size_t)row * N + col];
        if (OBF) ((u16*)Cout)[(size_t)row * N + col] = f2bf(v);
        else     ((float*)Cout)[(size_t)row * N + col] = v;
      }
    }
}

// ---------- fused attention: one block per (b,h); S=QK^T/8, softmax, O=PV ----------
__global__ __launch_bounds__(256) void attn_kernel(
    const u16* __restrict__ qkv, u16* __restrict__ attn_out)
{
  __shared__ u16 Ks[128 * 64];
  __shared__ u16 Vt[64 * 128];
  __shared__ u16 Ps[128 * 128];
  const int h = blockIdx.x, b = blockIdx.y;
  const int t = threadIdx.x, lane = t & 63, w = t >> 6;
  const int lr = lane & 15, lq = lane >> 4;
  const u16* base = qkv + (size_t)b * 128 * 1536 + h * 64;

  // stage K and V^T
#pragma unroll
  for (int i = 0; i < 4; ++i) {
    int ch = i * 256 + t;            // 0..1023
    int s = ch >> 3, off = (ch & 7) * 8;
    *(v8s*)(Ks + s * 64 + off) = *(const v8s*)(base + 512 + (size_t)s * 1536 + off);
    v8s vv = *(const v8s*)(base + 1024 + (size_t)s * 1536 + off);
#pragma unroll
    for (int j = 0; j < 8; ++j) Vt[(off + j) * 128 + s] = (u16)vv[j];
  }
  __syncthreads();

  // S = Q K^T  (Q frags straight from global)
  const v4f vzero = {0.f, 0.f, 0.f, 0.f};
  v4f sacc[2][8];
#pragma unroll
  for (int mt = 0; mt < 2; ++mt)
#pragma unroll
    for (int nt = 0; nt < 8; ++nt) sacc[mt][nt] = vzero;
#pragma unroll
  for (int kk = 0; kk < 64; kk += 32) {
    v8s a0 = *(const v8s*)(base + (size_t)(w * 32 + lr) * 1536 + kk + lq * 8);
    v8s a1 = *(const v8s*)(base + (size_t)(w * 32 + 16 + lr) * 1536 + kk + lq * 8);
#pragma unroll
    for (int nt = 0; nt < 8; ++nt) {
      v8s bb = *(const v8s*)(Ks + (nt * 16 + lr) * 64 + kk + lq * 8);
      sacc[0][nt] = mfma16(a0, bb, sacc[0][nt]);
      sacc[1][nt] = mfma16(a1, bb, sacc[1][nt]);
    }
  }

  // softmax per row (rows owned per-wave); scale 1/8
  float rinv[2][4];
#pragma unroll
  for (int mt = 0; mt < 2; ++mt)
#pragma unroll
    for (int r = 0; r < 4; ++r) {
      float mx = -3.0e38f;
#pragma unroll
      for (int nt = 0; nt < 8; ++nt) mx = fmaxf(mx, sacc[mt][nt][r]);
#pragma unroll
      for (int d = 1; d < 16; d <<= 1) mx = fmaxf(mx, __shfl_xor(mx, d, 64));
      float ls = 0.f;
      float pv[8];
#pragma unroll
      for (int nt = 0; nt < 8; ++nt) {
        pv[nt] = expf((sacc[mt][nt][r] - mx) * 0.125f);
        ls += pv[nt];
      }
#pragma unroll
      for (int d = 1; d < 16; d <<= 1) ls += __shfl_xor(ls, d, 64);
      rinv[mt][r] = 1.0f / ls;
      int row = w * 32 + mt * 16 + lq * 4 + r;
#pragma unroll
      for (int nt = 0; nt < 8; ++nt) Ps[row * 128 + nt * 16 + lr] = f2bf(pv[nt]);
    }
  __syncthreads();

  // O = P V
  v4f oacc[2][4];
#pragma unroll
  for (int mt = 0; mt < 2; ++mt)
#pragma unroll
    for (int nt = 0; nt < 4; ++nt) oacc[mt][nt] = vzero;
#pragma unroll
  for (int kk = 0; kk < 128; kk += 32) {
    v8s a0 = *(const v8s*)(Ps + (w * 32 + lr) * 128 + kk + lq * 8);
    v8s a1 = *(const v8s*)(Ps + (w * 32 + 16 + lr) * 128 + kk + lq * 8);
#pragma unroll
    for (int nt = 0; nt < 4; ++nt) {
      v8s bb = *(const v8s*)(Vt + (nt * 16 + lr) * 128 + kk + lq * 8);
      oacc[0][nt] = mfma16(a0, bb, oacc[0][nt]);
      oacc[1][nt] = mfma16(a1, bb, oacc[1][nt]);
    }
  }
#pragma unroll
  for (int mt = 0; mt < 2; ++mt)
#pragma unroll
    for (int nt = 0; nt < 4; ++nt)
#pragma unroll
      for (int r = 0; r < 4; ++r) {
        int row = w * 32 + mt * 16 + lq * 4 + r;
        int col = nt * 16 + lr;
        attn_out[((size_t)(b * 128 + row)) * 512 + h * 64 + col] =
            f2bf(oacc[mt][nt][r] * rinv[mt][r]);
      }
}

// ---------- bilinear 8x8 -> 32x32 (half-pixel centers, edge clamp == jax.image.resize) ----------
__global__ __launch_bounds__(256) void upsample_kernel(
    const float* __restrict__ xf, float* __restrict__ out)
{
  int bid = blockIdx.x;               // ((timg*32+b)*512+c)
  int c = bid & 511;
  int tb = bid >> 9;
  int b = tb & 31, timg = tb >> 5;
  __shared__ float tile[64];
  if (threadIdx.x < 64) {
    int s = timg * 64 + threadIdx.x;
    tile[threadIdx.x] = xf[((size_t)b * 128 + s) * 512 + c];
  }
  __syncthreads();
  float* obase = out + (size_t)timg * (32ull * 512 * 1024) + ((size_t)b * 512 + c) * 1024;
#pragma unroll
  for (int k = 0; k < 4; ++k) {
    int pix = threadIdx.x + k * 256;
    int i = pix >> 5, j = pix & 31;
    float cy = fminf(fmaxf((i - 1.5f) * 0.25f, 0.f), 7.f);
    float cx = fminf(fmaxf((j - 1.5f) * 0.25f, 0.f), 7.f);
    int y0 = (int)cy, x0 = (int)cx;
    int y1 = min(y0 + 1, 7), x1 = min(x0 + 1, 7);
    float fy = cy - y0, fx = cx - x0;
    float v00 = tile[y0 * 8 + x0], v01 = tile[y0 * 8 + x1];
    float v10 = tile[y1 * 8 + x0], v11 = tile[y1 * 8 + x1];
    obase[pix] = (v00 * (1.f - fx) + v01 * fx) * (1.f - fy) + (v10 * (1.f - fx) + v11 * fx) * fy;
  }
}

// ---------- host ----------
extern "C" void kernel_launch(void* const* d_in, const int* in_sizes, int n_in,
                              void* d_out, int out_size, void* d_ws, size_t ws_size,
                              hipStream_t stream)
{
  const float* rgb_fea = (const float*)d_in[0];
  const float* ir_fea  = (const float*)d_in[1];
  const float* pos_emb = (const float*)d_in[2];
  const float* conv1_w = (const float*)d_in[3];
  const float* conv2_w = (const float*)d_in[4];
  const float* ln1_w = (const float*)d_in[5];
  const float* ln1_b = (const float*)d_in[6];
  const float* Wq = (const float*)d_in[7];
  const float* bq = (const float*)d_in[8];
  const float* Wk = (const float*)d_in[9];
  const float* bk = (const float*)d_in[10];
  const float* Wv = (const float*)d_in[11];
  const float* bv = (const float*)d_in[12];
  const float* Wo = (const float*)d_in[13];
  const float* bo = (const float*)d_in[14];
  const float* ln2_w = (const float*)d_in[15];
  const float* ln2_b = (const float*)d_in[16];
  const float* W1 = (const float*)d_in[17];
  const float* b1 = (const float*)d_in[18];
  const float* W2 = (const float*)d_in[19];
  const float* b2 = (const float*)d_in[20];
  const float* lnf_w = (const float*)d_in[21];
  const float* lnf_b = (const float*)d_in[22];
  (void)in_sizes; (void)n_in; (void)out_size; (void)ws_size;

  char* wsb = (char*)d_ws;
  size_t off = 0;
  auto alloc = [&](size_t nbytes) -> void* {
    void* p = wsb + off;
    off += (nbytes + 255) & ~(size_t)255;
    return p;
  };
  float* pool   = (float*)alloc(2ull * 32 * 512 * 64 * 4);   // 8 MB
  float* Mplain = (float*)alloc(2ull * 32 * 8 * 64 * 4);
  float* Mhp    = (float*)alloc(2ull * 4 * 8 * 64 * 4);
  float* x      = (float*)alloc((size_t)MTOT * 512 * 4);     // 8 MB residual stream
  float* xf     = (float*)alloc((size_t)MTOT * 512 * 4);
  u16* ln_out   = (u16*)alloc((size_t)MTOT * 512 * 2);
  u16* qkv      = (u16*)alloc((size_t)MTOT * 1536 * 2);
  u16* attn     = (u16*)alloc((size_t)MTOT * 512 * 2);
  u16* hbuf     = (u16*)alloc((size_t)MTOT * 2048 * 2);
  u16* WqkvT    = (u16*)alloc(8ull * 1536 * 512 * 2);
  u16* WoT      = (u16*)alloc(8ull * 512 * 512 * 2);
  u16* W1T      = (u16*)alloc(8ull * 2048 * 512 * 2);
  u16* W2T      = (u16*)alloc(8ull * 512 * 2048 * 2);
  float* qb     = (float*)alloc(8ull * 1536 * 4);
  // total ~113.5 MB of workspace

  // weight prep: transpose (K,N)->(N,K) + bf16
  transpose_bf16_kernel<<<dim3(16, 16, 8), 256, 0, stream>>>(Wq, WqkvT, 512, 512, 512ull * 512, 1536ull * 512, 0);
  transpose_bf16_kernel<<<dim3(16, 16, 8), 256, 0, stream>>>(Wk, WqkvT, 512, 512, 512ull * 512, 1536ull * 512, 512);
  transpose_bf16_kernel<<<dim3(16, 16, 8), 256, 0, stream>>>(Wv, WqkvT, 512, 512, 512ull * 512, 1536ull * 512, 1024);
  transpose_bf16_kernel<<<dim3(16, 16, 8), 256, 0, stream>>>(Wo, WoT, 512, 512, 512ull * 512, 512ull * 512, 0);
  transpose_bf16_kernel<<<dim3(64, 16, 8), 256, 0, stream>>>(W1, W1T, 512, 2048, 512ull * 2048, 2048ull * 512, 0);
  transpose_bf16_kernel<<<dim3(16, 64, 8), 256, 0, stream>>>(W2, W2T, 2048, 512, 2048ull * 512, 512ull * 2048, 0);
  qkvbias_kernel<<<8, 256, 0, stream>>>(bq, bk, bv, qb);

  // front-end
  pool_kernel<<<8192, 256, 0, stream>>>(rgb_fea, ir_fea, pool);
  convm_kernel<<<72, 256, 0, stream>>>(pool, conv1_w, Mplain, Mhp);
  loss_kernel<<<1, 256, 0, stream>>>(Mplain, Mhp, (float*)d_out + 33554432);
  token_kernel<<<MTOT, 256, 0, stream>>>(pos_emb, conv2_w, Mplain, pool, x);

  // transformer
  for (int l = 0; l < 8; ++l) {
    ln_kernel<1><<<MTOT, 256, 0, stream>>>(x, ln1_w + l * 512, ln1_b + l * 512, ln_out);
    gemm_bt<0, 0, 1><<<dim3(12, 32), 256, 0, stream>>>(
        ln_out, WqkvT + (size_t)l * 1536 * 512, qb + l * 1536, nullptr, qkv, 1536, 512);
    attn_kernel<<<dim3(8, 32), 256, 0, stream>>>(qkv, attn);
    gemm_bt<0, 1, 0><<<dim3(4, 32), 256, 0, stream>>>(
        attn, WoT + (size_t)l * 512 * 512, bo + l * 512, x, x, 512, 512);
    ln_kernel<1><<<MTOT, 256, 0, stream>>>(x, ln2_w + l * 512, ln2_b + l * 512, ln_out);
    gemm_bt<1, 0, 1><<<dim3(16, 32), 256, 0, stream>>>(
        ln_out, W1T + (size_t)l * 2048 * 512, b1 + l * 2048, nullptr, hbuf, 2048, 512);
    gemm_bt<0, 1, 0><<<dim3(4, 32), 256, 0, stream>>>(
        hbuf, W2T + (size_t)l * 512 * 2048, b2 + l * 512, x, x, 512, 2048);
  }

  // final LN + upsample
  ln_kernel<0><<<MTOT, 256, 0, stream>>>(x, lnf_w, lnf_b, xf);
  upsample_kernel<<<32768, 256, 0, stream>>>(xf, (float*)d_out);
}

// Round 2
// 1374.131 us; speedup vs baseline: 1.1041x; 1.1041x over previous
//
#include <hip/hip_runtime.h>
#include <math.h>

typedef unsigned short u16;
typedef short v8s __attribute__((ext_vector_type(8)));
typedef float v4f __attribute__((ext_vector_type(4)));

#define MTOT 4096   // BS*SEQ = 32*128

// ---------- helpers ----------
__device__ __forceinline__ u16 f2bf(float f) {
  unsigned int u = __float_as_uint(f);
  u += 0x7fffu + ((u >> 16) & 1u);   // RNE
  return (u16)(u >> 16);
}

__device__ __forceinline__ v4f mfma16(v8s a, v8s b, v4f c) {
  return __builtin_amdgcn_mfma_f32_16x16x32_bf16(a, b, c, 0, 0, 0);
}

__device__ __forceinline__ void gl_lds16(const u16* g, u16* l) {
  __builtin_amdgcn_global_load_lds(
      (const __attribute__((address_space(1))) void*)g,
      (__attribute__((address_space(3))) void*)l, 16, 0, 0);
}

// theta = 3*pi/4 * ((y+x) mod 8)
__constant__ float c_ct[8] = {1.f, -0.70710678118654752f, 0.f, 0.70710678118654752f,
                              -1.f, 0.70710678118654752f, 0.f, -0.70710678118654752f};
__constant__ float c_st[8] = {0.f, 0.70710678118654752f, -1.f, 0.70710678118654752f,
                              0.f, -0.70710678118654752f, 1.f, -0.70710678118654752f};

// ---------- weight transpose + bf16 convert: src (L,K,N) f32 -> dst rows (rowOff+n) length K bf16 ----------
__global__ __launch_bounds__(256) void transpose_bf16_kernel(
    const float* __restrict__ src, u16* __restrict__ dst,
    int K, int N, size_t srcLS, size_t dstLS, int rowOff)
{
  int l = blockIdx.z;
  int n0 = blockIdx.x * 32, k0 = blockIdx.y * 32;
  __shared__ float tile[32][33];
  int tx = threadIdx.x & 31, ty = threadIdx.x >> 5;   // 32 x 8
  const float* s = src + (size_t)l * srcLS;
#pragma unroll
  for (int rr = 0; rr < 4; ++rr) {
    int k = k0 + ty + rr * 8;
    tile[ty + rr * 8][tx] = s[(size_t)k * N + n0 + tx];
  }
  __syncthreads();
  u16* dp = dst + (size_t)l * dstLS;
#pragma unroll
  for (int rr = 0; rr < 4; ++rr) {
    int n = n0 + ty + rr * 8;
    dp[(size_t)(rowOff + n) * K + k0 + tx] = f2bf(tile[tx][ty + rr * 8]);
  }
}

// ---------- merged q/k/v transpose: z -> (l, which) ----------
__global__ __launch_bounds__(256) void qkv_transpose_kernel(
    const float* __restrict__ Wq, const float* __restrict__ Wk,
    const float* __restrict__ Wv, u16* __restrict__ dst)
{
  int z = blockIdx.z;
  int l = z / 3, which = z % 3;
  const float* src = (which == 0) ? Wq : (which == 1) ? Wk : Wv;
  int n0 = blockIdx.x * 32, k0 = blockIdx.y * 32;
  __shared__ float tile[32][33];
  int tx = threadIdx.x & 31, ty = threadIdx.x >> 5;
  const float* s = src + (size_t)l * 512 * 512;
#pragma unroll
  for (int rr = 0; rr < 4; ++rr) {
    int k = k0 + ty + rr * 8;
    tile[ty + rr * 8][tx] = s[(size_t)k * 512 + n0 + tx];
  }
  __syncthreads();
  u16* dp = dst + (size_t)l * 1536 * 512;
  int rowOff = which * 512;
#pragma unroll
  for (int rr = 0; rr < 4; ++rr) {
    int n = n0 + ty + rr * 8;
    dp[(size_t)(rowOff + n) * 512 + k0 + tx] = f2bf(tile[tx][ty + rr * 8]);
  }
}

// ---------- concat qkv bias ----------
__global__ __launch_bounds__(256) void qkvbias_kernel(
    const float* __restrict__ bq, const float* __restrict__ bk,
    const float* __restrict__ bv, float* __restrict__ qb)
{
  int l = blockIdx.x;
  for (int j = threadIdx.x; j < 1536; j += 256) {
    float v = (j < 512) ? bq[l * 512 + j] : (j < 1024) ? bk[l * 512 + j - 512] : bv[l * 512 + j - 1024];
    qb[l * 1536 + j] = v;
  }
}

// ---------- 4x4 avg pool: out layout [t][b][c][hw], hw = y*8+x ----------
__global__ __launch_bounds__(256) void pool_kernel(
    const float* __restrict__ rgb, const float* __restrict__ ir, float* __restrict__ pool)
{
  int idx = blockIdx.x * 4 + (threadIdx.x >> 6);   // over 2*32*512
  int i = threadIdx.x & 63;
  int y = i >> 3, xcol = i & 7;
  int timg = idx >> 14;
  int rem = idx & 16383;                            // b*512+c
  const float* src = (timg ? ir : rgb) + (size_t)rem * 1024;
  float s = 0.f;
#pragma unroll
  for (int r = 0; r < 4; ++r) {
    float4 v = *(const float4*)(src + (y * 4 + r) * 32 + xcol * 4);
    s += v.x + v.y + v.z + v.w;
  }
  pool[(size_t)idx * 64 + i] = s * 0.0625f;
}

// ---------- highpass + conv1 partials: grid (72 rows, 8 c-chunks) ----------
// Macc[cc][r][o][hw] partial sums; kind1 rows include analytic DFT-bin removal.
__global__ __launch_bounds__(256) void convm_kernel(
    const float* __restrict__ pool, const float* __restrict__ conv1_w,
    float* __restrict__ Macc)
{
  int r = blockIdx.x;      // 0..71
  int cc = blockIdx.y;     // 0..7
  int t = threadIdx.x, hw = t & 63, cg = t >> 6;   // each wave = one cg, spans all hw
  int kind = (r < 64) ? 0 : 1;
  int prow;
  if (kind == 0) prow = r;
  else { int rh = r - 64; prow = (rh >> 2) * 32 + (rh & 3); }
  int yy = hw >> 3, xx = hw & 7;
  int sd = (yy + xx) & 7;
  float ct = c_ct[sd], st = c_st[sd];
  float acc[8] = {0.f,0.f,0.f,0.f,0.f,0.f,0.f,0.f};
  const float* pbase = pool + ((size_t)prow * 512 + cc * 64) * 64;
#pragma unroll 4
  for (int it = 0; it < 16; ++it) {
    int cl = cg * 16 + it;          // local c in chunk
    int c = cc * 64 + cl;
    float p = pbase[(size_t)cl * 64 + hw];
    float val = p;
    if (kind == 1) {
      float C = p * ct, S = p * st;
#pragma unroll
      for (int d = 1; d < 64; d <<= 1) { C += __shfl_xor(C, d, 64); S += __shfl_xor(S, d, 64); }
      float hp = p - (C * ct + S * st) * (1.0f / 64.0f);
      val = hp * p;
    }
#pragma unroll
    for (int o = 0; o < 8; ++o) acc[o] += conv1_w[o * 512 + c] * val;
  }
  __shared__ float red[4][8][64];
#pragma unroll
  for (int o = 0; o < 8; ++o) red[cg][o][hw] = acc[o];
  __syncthreads();
  if (cg == 0) {
#pragma unroll
    for (int o = 0; o < 8; ++o) {
      float s = red[0][o][hw] + red[1][o][hw] + red[2][o][hw] + red[3][o][hw];
      Macc[((size_t)cc * 72 + r) * 512 + o * 64 + hw] = s;
    }
  }
}

// ---------- sum 8 partials + sigmoid -> M ----------
__global__ __launch_bounds__(256) void msig_kernel(
    const float* __restrict__ Macc, float* __restrict__ Mplain, float* __restrict__ Mhp)
{
  int i = blockIdx.x * 256 + threadIdx.x;   // 0 .. 72*512-1
  float s = 0.f;
#pragma unroll
  for (int cc = 0; cc < 8; ++cc) s += Macc[(size_t)cc * 72 * 512 + i];
  float m = 1.0f / (1.0f + expf(-s));
  if (i < 64 * 512) Mplain[i] = m;
  else Mhp[i - 64 * 512] = m;
}

// ---------- patten_loss ----------
__global__ __launch_bounds__(256) void loss_kernel(
    const float* __restrict__ Mplain, const float* __restrict__ Mhp, float* __restrict__ out)
{
  int t = threadIdx.x, col = t & 63, rg = t >> 6;
  float sp = 0.f, sq = 0.f;
  for (int r = rg; r < 576; r += 4) {
    const float* rowp = (r < 512) ? (Mplain + (size_t)r * 64) : (Mhp + (size_t)(r - 512) * 64);
    float v = rowp[col];
    sp += v; sq += v * v;
  }
  __shared__ float scol[4][64], ssq[4][64];
  scol[rg][col] = sp; ssq[rg][col] = sq;
  __syncthreads();
  if (t < 64) {
    float s = scol[0][t] + scol[1][t] + scol[2][t] + scol[3][t];
    float q = ssq[0][t] + ssq[1][t] + ssq[2][t] + ssq[3][t];
    float ds = s * s;
#pragma unroll
    for (int d = 1; d < 64; d <<= 1) { ds += __shfl_xor(ds, d, 64); q += __shfl_xor(q, d, 64); }
    if (t == 0) *out = (ds - q) * 0.5f / (576.0f * 575.0f);
  }
}

// ---------- token build ----------
__global__ __launch_bounds__(256) void token_kernel(
    const float* __restrict__ pos_emb, const float* __restrict__ conv2_w,
    const float* __restrict__ Mplain, const float* __restrict__ pool, float* __restrict__ x)
{
  int bs_idx = blockIdx.x;           // b*128+s
  int b = bs_idx >> 7, s = bs_idx & 127;
  int timg = s >> 6, hw = s & 63;
  __shared__ float Ms[8];
  if (threadIdx.x < 8)
    Ms[threadIdx.x] = Mplain[((size_t)(timg * 32 + b) * 8 + threadIdx.x) * 64 + hw];
  __syncthreads();
#pragma unroll
  for (int i = 0; i < 2; ++i) {
    int d = threadIdx.x + i * 256;
    float acc = 0.f;
#pragma unroll
    for (int o = 0; o < 8; ++o) acc += conv2_w[d * 8 + o] * Ms[o];
    float p = pool[(((size_t)timg * 32 + b) * 512 + d) * 64 + hw];
    x[(size_t)bs_idx * 512 + d] = pos_emb[s * 512 + d] + acc * p;
  }
}

// ---------- LayerNorm over 512; out bf16 or f32 ----------
template<int OBF>
__global__ __launch_bounds__(256) void ln_kernel(
    const float* __restrict__ xin, const float* __restrict__ w,
    const float* __restrict__ bb, void* __restrict__ out)
{
  int row = blockIdx.x, t = threadIdx.x;
  float2 v = ((const float2*)(xin + (size_t)row * 512))[t];
  float s = v.x + v.y, q = v.x * v.x + v.y * v.y;
#pragma unroll
  for (int d = 1; d < 64; d <<= 1) { s += __shfl_xor(s, d, 64); q += __shfl_xor(q, d, 64); }
  __shared__ float ps[4], pq[4];
  int wv = t >> 6;
  if ((t & 63) == 0) { ps[wv] = s; pq[wv] = q; }
  __syncthreads();
  float S = ps[0] + ps[1] + ps[2] + ps[3];
  float Q = pq[0] + pq[1] + pq[2] + pq[3];
  float mean = S * (1.0f / 512.0f);
  float var = Q * (1.0f / 512.0f) - mean * mean;
  float rstd = rsqrtf(var + 1e-5f);
  float o0 = (v.x - mean) * rstd * w[t * 2] + bb[t * 2];
  float o1 = (v.y - mean) * rstd * w[t * 2 + 1] + bb[t * 2 + 1];
  if (OBF) { u16* o = (u16*)out + (size_t)row * 512; o[t * 2] = f2bf(o0); o[t * 2 + 1] = f2bf(o1); }
  else     { float* o = (float*)out + (size_t)row * 512; o[t * 2] = o0; o[t * 2 + 1] = o1; }
}

// ---------- GEMM 128x128: C = A(MxK,bf16) * BT(NxK,bf16)^T + bias [+gelu] [+resid] ----------
template<int ACT, int RESID, int OBF>
__global__ __launch_bounds__(256) void gemm_bt(
    const u16* __restrict__ A, const u16* __restrict__ BT,
    const float* __restrict__ bias, const float* __restrict__ resid,
    void* __restrict__ Cout, int N, int K)
{
  __shared__ u16 As[128 * 32];
  __shared__ u16 Bs[128 * 32];
  const int m0 = blockIdx.y * 128, n0 = blockIdx.x * 128;
  const int t = threadIdx.x, lane = t & 63, w = t >> 6;
  const int lr = lane & 15, lq = lane >> 4;
  const int wm = (w & 1) * 64, wn = (w >> 1) * 64;
  v4f acc[4][4];
  const v4f vzero = {0.f, 0.f, 0.f, 0.f};
#pragma unroll
  for (int mt = 0; mt < 4; ++mt)
#pragma unroll
    for (int nt = 0; nt < 4; ++nt) acc[mt][nt] = vzero;

  for (int kk = 0; kk < K; kk += 32) {
    __syncthreads();
    {
      int r0 = t >> 2, c0 = (t & 3) << 3;
      gl_lds16(A  + (size_t)(m0 + r0) * K + kk + c0, As + (size_t)(w * 64) * 8);
      gl_lds16(BT + (size_t)(n0 + r0) * K + kk + c0, Bs + (size_t)(w * 64) * 8);
      int ch = 256 + t;
      int r1 = ch >> 2, c1 = (ch & 3) << 3;
      gl_lds16(A  + (size_t)(m0 + r1) * K + kk + c1, As + (size_t)(256 + w * 64) * 8);
      gl_lds16(BT + (size_t)(n0 + r1) * K + kk + c1, Bs + (size_t)(256 + w * 64) * 8);
    }
    __syncthreads();
    v8s a[4], b[4];
#pragma unroll
    for (int mt = 0; mt < 4; ++mt)
      a[mt] = *(const v8s*)(As + (wm + mt * 16 + lr) * 32 + lq * 8);
#pragma unroll
    for (int nt = 0; nt < 4; ++nt)
      b[nt] = *(const v8s*)(Bs + (wn + nt * 16 + lr) * 32 + lq * 8);
#pragma unroll
    for (int mt = 0; mt < 4; ++mt)
#pragma unroll
      for (int nt = 0; nt < 4; ++nt)
        acc[mt][nt] = mfma16(a[mt], b[nt], acc[mt][nt]);
  }

#pragma unroll
  for (int mt = 0; mt < 4; ++mt)
#pragma unroll
    for (int nt = 0; nt < 4; ++nt) {
      int col = n0 + wn + nt * 16 + lr;
      float bsv = bias[col];
#pragma unroll
      for (int r = 0; r < 4; ++r) {
        int row = m0 + wm + mt * 16 + lq * 4 + r;
        float v = acc[mt][nt][r] + bsv;
        if (ACT == 1) v = 0.5f * v * (1.0f + erff(v * 0.70710678118654752f));
        if (RESID) v += resid[(size_t)row * N + col];
        if (OBF) ((u16*)Cout)[(size_t)row * N + col] = f2bf(v);
        else     ((float*)Cout)[(size_t)row * N + col] = v;
      }
    }
}

// ---------- GEMM 128x64 tile (for N=512: 256 blocks -> full chip) ----------
template<int ACT, int RESID, int OBF>
__global__ __launch_bounds__(256) void gemm_bt64(
    const u16* __restrict__ A, const u16* __restrict__ BT,
    const float* __restrict__ bias, const float* __restrict__ resid,
    void* __restrict__ Cout, int N, int K)
{
  __shared__ u16 As[128 * 32];
  __shared__ u16 Bs[64 * 32];
  const int m0 = blockIdx.y * 128, n0 = blockIdx.x * 64;
  const int t = threadIdx.x, lane = t & 63, w = t >> 6;
  const int lr = lane & 15, lq = lane >> 4;
  const int wm = (w & 1) * 64, wn = (w >> 1) * 32;
  v4f acc[4][2];
  const v4f vzero = {0.f, 0.f, 0.f, 0.f};
#pragma unroll
  for (int mt = 0; mt < 4; ++mt)
#pragma unroll
    for (int nt = 0; nt < 2; ++nt) acc[mt][nt] = vzero;

  for (int kk = 0; kk < K; kk += 32) {
    __syncthreads();
    {
      int r0 = t >> 2, c0 = (t & 3) << 3;
      gl_lds16(A  + (size_t)(m0 + r0) * K + kk + c0, As + (size_t)(w * 64) * 8);
      gl_lds16(BT + (size_t)(n0 + r0) * K + kk + c0, Bs + (size_t)(w * 64) * 8);
      int ch = 256 + t;
      int r1 = ch >> 2, c1 = (ch & 3) << 3;
      gl_lds16(A  + (size_t)(m0 + r1) * K + kk + c1, As + (size_t)(256 + w * 64) * 8);
    }
    __syncthreads();
    v8s a[4], b[2];
#pragma unroll
    for (int mt = 0; mt < 4; ++mt)
      a[mt] = *(const v8s*)(As + (wm + mt * 16 + lr) * 32 + lq * 8);
#pragma unroll
    for (int nt = 0; nt < 2; ++nt)
      b[nt] = *(const v8s*)(Bs + (wn + nt * 16 + lr) * 32 + lq * 8);
#pragma unroll
    for (int mt = 0; mt < 4; ++mt)
#pragma unroll
      for (int nt = 0; nt < 2; ++nt)
        acc[mt][nt] = mfma16(a[mt], b[nt], acc[mt][nt]);
  }

#pragma unroll
  for (int mt = 0; mt < 4; ++mt)
#pragma unroll
    for (int nt = 0; nt < 2; ++nt) {
      int col = n0 + wn + nt * 16 + lr;
      float bsv = bias[col];
#pragma unroll
      for (int r = 0; r < 4; ++r) {
        int row = m0 + wm + mt * 16 + lq * 4 + r;
        float v = acc[mt][nt][r] + bsv;
        if (ACT == 1) v = 0.5f * v * (1.0f + erff(v * 0.70710678118654752f));
        if (RESID) v += resid[(size_t)row * N + col];
        if (OBF) ((u16*)Cout)[(size_t)row * N + col] = f2bf(v);
        else     ((float*)Cout)[(size_t)row * N + col] = v;
      }
    }
}

// ---------- fused attention: one block per (b,h) ----------
__global__ __launch_bounds__(256) void attn_kernel(
    const u16* __restrict__ qkv, u16* __restrict__ attn_out)
{
  __shared__ u16 Ks[128 * 64];
  __shared__ u16 Vt[64 * 128];
  __shared__ u16 Ps[128 * 128];
  const int h = blockIdx.x, b = blockIdx.y;
  const int t = threadIdx.x, lane = t & 63, w = t >> 6;
  const int lr = lane & 15, lq = lane >> 4;
  const u16* base = qkv + (size_t)b * 128 * 1536 + h * 64;

#pragma unroll
  for (int i = 0; i < 4; ++i) {
    int ch = i * 256 + t;            // 0..1023
    int s = ch >> 3, off = (ch & 7) * 8;
    *(v8s*)(Ks + s * 64 + off) = *(const v8s*)(base + 512 + (size_t)s * 1536 + off);
    v8s vv = *(const v8s*)(base + 1024 + (size_t)s * 1536 + off);
#pragma unroll
    for (int j = 0; j < 8; ++j) Vt[(off + j) * 128 + s] = (u16)vv[j];
  }
  __syncthreads();

  const v4f vzero = {0.f, 0.f, 0.f, 0.f};
  v4f sacc[2][8];
#pragma unroll
  for (int mt = 0; mt < 2; ++mt)
#pragma unroll
    for (int nt = 0; nt < 8; ++nt) sacc[mt][nt] = vzero;
#pragma unroll
  for (int kk = 0; kk < 64; kk += 32) {
    v8s a0 = *(const v8s*)(base + (size_t)(w * 32 + lr) * 1536 + kk + lq * 8);
    v8s a1 = *(const v8s*)(base + (size_t)(w * 32 + 16 + lr) * 1536 + kk + lq * 8);
#pragma unroll
    for (int nt = 0; nt < 8; ++nt) {
      v8s bb = *(const v8s*)(Ks + (nt * 16 + lr) * 64 + kk + lq * 8);
      sacc[0][nt] = mfma16(a0, bb, sacc[0][nt]);
      sacc[1][nt] = mfma16(a1, bb, sacc[1][nt]);
    }
  }

  float rinv[2][4];
#pragma unroll
  for (int mt = 0; mt < 2; ++mt)
#pragma unroll
    for (int r = 0; r < 4; ++r) {
      float mx = -3.0e38f;
#pragma unroll
      for (int nt = 0; nt < 8; ++nt) mx = fmaxf(mx, sacc[mt][nt][r]);
#pragma unroll
      for (int d = 1; d < 16; d <<= 1) mx = fmaxf(mx, __shfl_xor(mx, d, 64));
      float ls = 0.f;
      float pv[8];
#pragma unroll
      for (int nt = 0; nt < 8; ++nt) {
        pv[nt] = expf((sacc[mt][nt][r] - mx) * 0.125f);
        ls += pv[nt];
      }
#pragma unroll
      for (int d = 1; d < 16; d <<= 1) ls += __shfl_xor(ls, d, 64);
      rinv[mt][r] = 1.0f / ls;
      int row = w * 32 + mt * 16 + lq * 4 + r;
#pragma unroll
      for (int nt = 0; nt < 8; ++nt) Ps[row * 128 + nt * 16 + lr] = f2bf(pv[nt]);
    }
  __syncthreads();

  v4f oacc[2][4];
#pragma unroll
  for (int mt = 0; mt < 2; ++mt)
#pragma unroll
    for (int nt = 0; nt < 4; ++nt) oacc[mt][nt] = vzero;
#pragma unroll
  for (int kk = 0; kk < 128; kk += 32) {
    v8s a0 = *(const v8s*)(Ps + (w * 32 + lr) * 128 + kk + lq * 8);
    v8s a1 = *(const v8s*)(Ps + (w * 32 + 16 + lr) * 128 + kk + lq * 8);
#pragma unroll
    for (int nt = 0; nt < 4; ++nt) {
      v8s bb = *(const v8s*)(Vt + (nt * 16 + lr) * 128 + kk + lq * 8);
      oacc[0][nt] = mfma16(a0, bb, oacc[0][nt]);
      oacc[1][nt] = mfma16(a1, bb, oacc[1][nt]);
    }
  }
#pragma unroll
  for (int mt = 0; mt < 2; ++mt)
#pragma unroll
    for (int nt = 0; nt < 4; ++nt)
#pragma unroll
      for (int r = 0; r < 4; ++r) {
        int row = w * 32 + mt * 16 + lq * 4 + r;
        int col = nt * 16 + lr;
        attn_out[((size_t)(b * 128 + row)) * 512 + h * 64 + col] =
            f2bf(oacc[mt][nt][r] * rinv[mt][r]);
      }
}

// ---------- bilinear 8x8 -> 32x32 ----------
__global__ __launch_bounds__(256) void upsample_kernel(
    const float* __restrict__ xf, float* __restrict__ out)
{
  int bid = blockIdx.x;               // ((timg*32+b)*512+c)
  int c = bid & 511;
  int tb = bid >> 9;
  int b = tb & 31, timg = tb >> 5;
  __shared__ float tile[64];
  if (threadIdx.x < 64) {
    int s = timg * 64 + threadIdx.x;
    tile[threadIdx.x] = xf[((size_t)b * 128 + s) * 512 + c];
  }
  __syncthreads();
  float* obase = out + (size_t)timg * (32ull * 512 * 1024) + ((size_t)b * 512 + c) * 1024;
#pragma unroll
  for (int k = 0; k < 4; ++k) {
    int pix = threadIdx.x + k * 256;
    int i = pix >> 5, j = pix & 31;
    float cy = fminf(fmaxf((i - 1.5f) * 0.25f, 0.f), 7.f);
    float cx = fminf(fmaxf((j - 1.5f) * 0.25f, 0.f), 7.f);
    int y0 = (int)cy, x0 = (int)cx;
    int y1 = min(y0 + 1, 7), x1 = min(x0 + 1, 7);
    float fy = cy - y0, fx = cx - x0;
    float v00 = tile[y0 * 8 + x0], v01 = tile[y0 * 8 + x1];
    float v10 = tile[y1 * 8 + x0], v11 = tile[y1 * 8 + x1];
    obase[pix] = (v00 * (1.f - fx) + v01 * fx) * (1.f - fy) + (v10 * (1.f - fx) + v11 * fx) * fy;
  }
}

// ---------- host ----------
extern "C" void kernel_launch(void* const* d_in, const int* in_sizes, int n_in,
                              void* d_out, int out_size, void* d_ws, size_t ws_size,
                              hipStream_t stream)
{
  const float* rgb_fea = (const float*)d_in[0];
  const float* ir_fea  = (const float*)d_in[1];
  const float* pos_emb = (const float*)d_in[2];
  const float* conv1_w = (const float*)d_in[3];
  const float* conv2_w = (const float*)d_in[4];
  const float* ln1_w = (const float*)d_in[5];
  const float* ln1_b = (const float*)d_in[6];
  const float* Wq = (const float*)d_in[7];
  const float* bq = (const float*)d_in[8];
  const float* Wk = (const float*)d_in[9];
  const float* bk = (const float*)d_in[10];
  const float* Wv = (const float*)d_in[11];
  const float* bv = (const float*)d_in[12];
  const float* Wo = (const float*)d_in[13];
  const float* bo = (const float*)d_in[14];
  const float* ln2_w = (const float*)d_in[15];
  const float* ln2_b = (const float*)d_in[16];
  const float* W1 = (const float*)d_in[17];
  const float* b1 = (const float*)d_in[18];
  const float* W2 = (const float*)d_in[19];
  const float* b2 = (const float*)d_in[20];
  const float* lnf_w = (const float*)d_in[21];
  const float* lnf_b = (const float*)d_in[22];
  (void)in_sizes; (void)n_in; (void)out_size; (void)ws_size;

  char* wsb = (char*)d_ws;
  size_t off = 0;
  auto alloc = [&](size_t nbytes) -> void* {
    void* p = wsb + off;
    off += (nbytes + 255) & ~(size_t)255;
    return p;
  };
  float* pool   = (float*)alloc(2ull * 32 * 512 * 64 * 4);   // 8 MB
  float* Macc   = (float*)alloc(8ull * 72 * 512 * 4);        // 1.2 MB
  float* Mplain = (float*)alloc(2ull * 32 * 8 * 64 * 4);
  float* Mhp    = (float*)alloc(2ull * 4 * 8 * 64 * 4);
  float* x      = (float*)alloc((size_t)MTOT * 512 * 4);
  float* xf     = (float*)alloc((size_t)MTOT * 512 * 4);
  u16* ln_out   = (u16*)alloc((size_t)MTOT * 512 * 2);
  u16* qkv      = (u16*)alloc((size_t)MTOT * 1536 * 2);
  u16* attn     = (u16*)alloc((size_t)MTOT * 512 * 2);
  u16* hbuf     = (u16*)alloc((size_t)MTOT * 2048 * 2);
  u16* WqkvT    = (u16*)alloc(8ull * 1536 * 512 * 2);
  u16* WoT      = (u16*)alloc(8ull * 512 * 512 * 2);
  u16* W1T      = (u16*)alloc(8ull * 2048 * 512 * 2);
  u16* W2T      = (u16*)alloc(8ull * 512 * 2048 * 2);
  float* qb     = (float*)alloc(8ull * 1536 * 4);

  // weight prep
  qkv_transpose_kernel<<<dim3(16, 16, 24), 256, 0, stream>>>(Wq, Wk, Wv, WqkvT);
  transpose_bf16_kernel<<<dim3(16, 16, 8), 256, 0, stream>>>(Wo, WoT, 512, 512, 512ull * 512, 512ull * 512, 0);
  transpose_bf16_kernel<<<dim3(64, 16, 8), 256, 0, stream>>>(W1, W1T, 512, 2048, 512ull * 2048, 2048ull * 512, 0);
  transpose_bf16_kernel<<<dim3(16, 64, 8), 256, 0, stream>>>(W2, W2T, 2048, 512, 2048ull * 512, 512ull * 2048, 0);
  qkvbias_kernel<<<8, 256, 0, stream>>>(bq, bk, bv, qb);

  // front-end
  pool_kernel<<<8192, 256, 0, stream>>>(rgb_fea, ir_fea, pool);
  convm_kernel<<<dim3(72, 8), 256, 0, stream>>>(pool, conv1_w, Macc);
  msig_kernel<<<144, 256, 0, stream>>>(Macc, Mplain, Mhp);
  loss_kernel<<<1, 256, 0, stream>>>(Mplain, Mhp, (float*)d_out + 33554432);
  token_kernel<<<MTOT, 256, 0, stream>>>(pos_emb, conv2_w, Mplain, pool, x);

  // transformer
  for (int l = 0; l < 8; ++l) {
    ln_kernel<1><<<MTOT, 256, 0, stream>>>(x, ln1_w + l * 512, ln1_b + l * 512, ln_out);
    gemm_bt<0, 0, 1><<<dim3(12, 32), 256, 0, stream>>>(
        ln_out, WqkvT + (size_t)l * 1536 * 512, qb + l * 1536, nullptr, qkv, 1536, 512);
    attn_kernel<<<dim3(8, 32), 256, 0, stream>>>(qkv, attn);
    gemm_bt64<0, 1, 0><<<dim3(8, 32), 256, 0, stream>>>(
        attn, WoT + (size_t)l * 512 * 512, bo + l * 512, x, x, 512, 512);
    ln_kernel<1><<<MTOT, 256, 0, stream>>>(x, ln2_w + l * 512, ln2_b + l * 512, ln_out);
    gemm_bt<1, 0, 1><<<dim3(16, 32), 256, 0, stream>>>(
        ln_out, W1T + (size_t)l * 2048 * 512, b1 + l * 2048, nullptr, hbuf, 2048, 512);
    gemm_bt64<0, 1, 0><<<dim3(8, 32), 256, 0, stream>>>(
        hbuf, W2T + (size_t)l * 512 * 2048, b2 + l * 512, x, x, 512, 2048);
  }

  // final LN + upsample
  ln_kernel<0><<<MTOT, 256, 0, stream>>>(x, lnf_w, lnf_b, xf);
  upsample_kernel<<<32768, 256, 0, stream>>>(xf, (float*)d_out);
}

// Round 3
// 1306.761 us; speedup vs baseline: 1.1610x; 1.0516x over previous
//
#include <hip/hip_runtime.h>
#include <math.h>

typedef unsigned short u16;
typedef short v8s __attribute__((ext_vector_type(8)));
typedef unsigned short v8u __attribute__((ext_vector_type(8)));
typedef float v4f __attribute__((ext_vector_type(4)));

#define MTOT 4096   // BS*SEQ = 32*128

// ---------- helpers ----------
__device__ __forceinline__ u16 f2bf(float f) {
  unsigned int u = __float_as_uint(f);
  u += 0x7fffu + ((u >> 16) & 1u);   // RNE
  return (u16)(u >> 16);
}

__device__ __forceinline__ v4f mfma16(v8s a, v8s b, v4f c) {
  return __builtin_amdgcn_mfma_f32_16x16x32_bf16(a, b, c, 0, 0, 0);
}

__device__ __forceinline__ void gl_lds16(const u16* g, u16* l) {
  __builtin_amdgcn_global_load_lds(
      (const __attribute__((address_space(1))) void*)g,
      (__attribute__((address_space(3))) void*)l, 16, 0, 0);
}

__device__ __forceinline__ float fast_gelu(float v) {
  // tanh-form GELU; |err| vs exact erf-GELU ~5e-4, below bf16 rounding of h
  float y = 0.7978845608028654f * (v + 0.044715f * v * v * v);
  float t = 1.0f - 2.0f / (__expf(2.0f * y) + 1.0f);
  return 0.5f * v * (1.0f + t);
}

// theta = 3*pi/4 * ((y+x) mod 8)
__constant__ float c_ct[8] = {1.f, -0.70710678118654752f, 0.f, 0.70710678118654752f,
                              -1.f, 0.70710678118654752f, 0.f, -0.70710678118654752f};
__constant__ float c_st[8] = {0.f, 0.70710678118654752f, -1.f, 0.70710678118654752f,
                              0.f, -0.70710678118654752f, 1.f, -0.70710678118654752f};

// ---------- weight transpose + bf16 convert ----------
__global__ __launch_bounds__(256) void transpose_bf16_kernel(
    const float* __restrict__ src, u16* __restrict__ dst,
    int K, int N, size_t srcLS, size_t dstLS, int rowOff)
{
  int l = blockIdx.z;
  int n0 = blockIdx.x * 32, k0 = blockIdx.y * 32;
  __shared__ float tile[32][33];
  int tx = threadIdx.x & 31, ty = threadIdx.x >> 5;   // 32 x 8
  const float* s = src + (size_t)l * srcLS;
#pragma unroll
  for (int rr = 0; rr < 4; ++rr) {
    int k = k0 + ty + rr * 8;
    tile[ty + rr * 8][tx] = s[(size_t)k * N + n0 + tx];
  }
  __syncthreads();
  u16* dp = dst + (size_t)l * dstLS;
#pragma unroll
  for (int rr = 0; rr < 4; ++rr) {
    int n = n0 + ty + rr * 8;
    dp[(size_t)(rowOff + n) * K + k0 + tx] = f2bf(tile[tx][ty + rr * 8]);
  }
}

// ---------- merged q/k/v transpose ----------
__global__ __launch_bounds__(256) void qkv_transpose_kernel(
    const float* __restrict__ Wq, const float* __restrict__ Wk,
    const float* __restrict__ Wv, u16* __restrict__ dst)
{
  int z = blockIdx.z;
  int l = z / 3, which = z % 3;
  const float* src = (which == 0) ? Wq : (which == 1) ? Wk : Wv;
  int n0 = blockIdx.x * 32, k0 = blockIdx.y * 32;
  __shared__ float tile[32][33];
  int tx = threadIdx.x & 31, ty = threadIdx.x >> 5;
  const float* s = src + (size_t)l * 512 * 512;
#pragma unroll
  for (int rr = 0; rr < 4; ++rr) {
    int k = k0 + ty + rr * 8;
    tile[ty + rr * 8][tx] = s[(size_t)k * 512 + n0 + tx];
  }
  __syncthreads();
  u16* dp = dst + (size_t)l * 1536 * 512;
  int rowOff = which * 512;
#pragma unroll
  for (int rr = 0; rr < 4; ++rr) {
    int n = n0 + ty + rr * 8;
    dp[(size_t)(rowOff + n) * 512 + k0 + tx] = f2bf(tile[tx][ty + rr * 8]);
  }
}

// ---------- concat qkv bias ----------
__global__ __launch_bounds__(256) void qkvbias_kernel(
    const float* __restrict__ bq, const float* __restrict__ bk,
    const float* __restrict__ bv, float* __restrict__ qb)
{
  int l = blockIdx.x;
  for (int j = threadIdx.x; j < 1536; j += 256) {
    float v = (j < 512) ? bq[l * 512 + j] : (j < 1024) ? bk[l * 512 + j - 512] : bv[l * 512 + j - 1024];
    qb[l * 1536 + j] = v;
  }
}

// ---------- 4x4 avg pool ----------
__global__ __launch_bounds__(256) void pool_kernel(
    const float* __restrict__ rgb, const float* __restrict__ ir, float* __restrict__ pool)
{
  int idx = blockIdx.x * 4 + (threadIdx.x >> 6);   // over 2*32*512
  int i = threadIdx.x & 63;
  int y = i >> 3, xcol = i & 7;
  int timg = idx >> 14;
  int rem = idx & 16383;                            // b*512+c
  const float* src = (timg ? ir : rgb) + (size_t)rem * 1024;
  float s = 0.f;
#pragma unroll
  for (int r = 0; r < 4; ++r) {
    float4 v = *(const float4*)(src + (y * 4 + r) * 32 + xcol * 4);
    s += v.x + v.y + v.z + v.w;
  }
  pool[(size_t)idx * 64 + i] = s * 0.0625f;
}

// ---------- highpass + conv1 partials: grid (72 rows, 8 c-chunks) ----------
__global__ __launch_bounds__(256) void convm_kernel(
    const float* __restrict__ pool, const float* __restrict__ conv1_w,
    float* __restrict__ Macc)
{
  int r = blockIdx.x;      // 0..71
  int cc = blockIdx.y;     // 0..7
  int t = threadIdx.x, hw = t & 63, cg = t >> 6;
  int kind = (r < 64) ? 0 : 1;
  int prow;
  if (kind == 0) prow = r;
  else { int rh = r - 64; prow = (rh >> 2) * 32 + (rh & 3); }
  int yy = hw >> 3, xx = hw & 7;
  int sd = (yy + xx) & 7;
  float ct = c_ct[sd], st = c_st[sd];
  float acc[8] = {0.f,0.f,0.f,0.f,0.f,0.f,0.f,0.f};
  const float* pbase = pool + ((size_t)prow * 512 + cc * 64) * 64;
#pragma unroll 4
  for (int it = 0; it < 16; ++it) {
    int cl = cg * 16 + it;
    int c = cc * 64 + cl;
    float p = pbase[(size_t)cl * 64 + hw];
    float val = p;
    if (kind == 1) {
      float C = p * ct, S = p * st;
#pragma unroll
      for (int d = 1; d < 64; d <<= 1) { C += __shfl_xor(C, d, 64); S += __shfl_xor(S, d, 64); }
      float hp = p - (C * ct + S * st) * (1.0f / 64.0f);
      val = hp * p;
    }
#pragma unroll
    for (int o = 0; o < 8; ++o) acc[o] += conv1_w[o * 512 + c] * val;
  }
  __shared__ float red[4][8][64];
#pragma unroll
  for (int o = 0; o < 8; ++o) red[cg][o][hw] = acc[o];
  __syncthreads();
  if (cg == 0) {
#pragma unroll
    for (int o = 0; o < 8; ++o) {
      float s = red[0][o][hw] + red[1][o][hw] + red[2][o][hw] + red[3][o][hw];
      Macc[((size_t)cc * 72 + r) * 512 + o * 64 + hw] = s;
    }
  }
}

// ---------- sum 8 partials + sigmoid -> M ----------
__global__ __launch_bounds__(256) void msig_kernel(
    const float* __restrict__ Macc, float* __restrict__ Mplain, float* __restrict__ Mhp)
{
  int i = blockIdx.x * 256 + threadIdx.x;
  float s = 0.f;
#pragma unroll
  for (int cc = 0; cc < 8; ++cc) s += Macc[(size_t)cc * 72 * 512 + i];
  float m = 1.0f / (1.0f + expf(-s));
  if (i < 64 * 512) Mplain[i] = m;
  else Mhp[i - 64 * 512] = m;
}

// ---------- patten_loss ----------
__global__ __launch_bounds__(256) void loss_kernel(
    const float* __restrict__ Mplain, const float* __restrict__ Mhp, float* __restrict__ out)
{
  int t = threadIdx.x, col = t & 63, rg = t >> 6;
  float sp = 0.f, sq = 0.f;
  for (int r = rg; r < 576; r += 4) {
    const float* rowp = (r < 512) ? (Mplain + (size_t)r * 64) : (Mhp + (size_t)(r - 512) * 64);
    float v = rowp[col];
    sp += v; sq += v * v;
  }
  __shared__ float scol[4][64], ssq[4][64];
  scol[rg][col] = sp; ssq[rg][col] = sq;
  __syncthreads();
  if (t < 64) {
    float s = scol[0][t] + scol[1][t] + scol[2][t] + scol[3][t];
    float q = ssq[0][t] + ssq[1][t] + ssq[2][t] + ssq[3][t];
    float ds = s * s;
#pragma unroll
    for (int d = 1; d < 64; d <<= 1) { ds += __shfl_xor(ds, d, 64); q += __shfl_xor(q, d, 64); }
    if (t == 0) *out = (ds - q) * 0.5f / (576.0f * 575.0f);
  }
}

// ---------- token build ----------
__global__ __launch_bounds__(256) void token_kernel(
    const float* __restrict__ pos_emb, const float* __restrict__ conv2_w,
    const float* __restrict__ Mplain, const float* __restrict__ pool, float* __restrict__ x)
{
  int bs_idx = blockIdx.x;           // b*128+s
  int b = bs_idx >> 7, s = bs_idx & 127;
  int timg = s >> 6, hw = s & 63;
  __shared__ float Ms[8];
  if (threadIdx.x < 8)
    Ms[threadIdx.x] = Mplain[((size_t)(timg * 32 + b) * 8 + threadIdx.x) * 64 + hw];
  __syncthreads();
#pragma unroll
  for (int i = 0; i < 2; ++i) {
    int d = threadIdx.x + i * 256;
    float acc = 0.f;
#pragma unroll
    for (int o = 0; o < 8; ++o) acc += conv2_w[d * 8 + o] * Ms[o];
    float p = pool[(((size_t)timg * 32 + b) * 512 + d) * 64 + hw];
    x[(size_t)bs_idx * 512 + d] = pos_emb[s * 512 + d] + acc * p;
  }
}

// ---------- LayerNorm over 512: one WAVE per row, no LDS/barrier ----------
template<int OBF>
__global__ __launch_bounds__(256) void ln_kernel(
    const float* __restrict__ xin, const float* __restrict__ w,
    const float* __restrict__ bb, void* __restrict__ out)
{
  int wv = threadIdx.x >> 6, lane = threadIdx.x & 63;
  int row = blockIdx.x * 4 + wv;
  const float4* rp = (const float4*)(xin + (size_t)row * 512);
  float4 v0 = rp[lane * 2], v1 = rp[lane * 2 + 1];
  float s = v0.x + v0.y + v0.z + v0.w + v1.x + v1.y + v1.z + v1.w;
  float q = v0.x*v0.x + v0.y*v0.y + v0.z*v0.z + v0.w*v0.w
          + v1.x*v1.x + v1.y*v1.y + v1.z*v1.z + v1.w*v1.w;
#pragma unroll
  for (int d = 1; d < 64; d <<= 1) { s += __shfl_xor(s, d, 64); q += __shfl_xor(q, d, 64); }
  float mean = s * (1.0f / 512.0f);
  float var = q * (1.0f / 512.0f) - mean * mean;
  float rstd = rsqrtf(var + 1e-5f);
  const float4* wp = (const float4*)w;
  const float4* bp = (const float4*)bb;
  float4 w0 = wp[lane * 2], w1 = wp[lane * 2 + 1];
  float4 b0 = bp[lane * 2], b1 = bp[lane * 2 + 1];
  float o0 = (v0.x - mean) * rstd * w0.x + b0.x;
  float o1 = (v0.y - mean) * rstd * w0.y + b0.y;
  float o2 = (v0.z - mean) * rstd * w0.z + b0.z;
  float o3 = (v0.w - mean) * rstd * w0.w + b0.w;
  float o4 = (v1.x - mean) * rstd * w1.x + b1.x;
  float o5 = (v1.y - mean) * rstd * w1.y + b1.y;
  float o6 = (v1.z - mean) * rstd * w1.z + b1.z;
  float o7 = (v1.w - mean) * rstd * w1.w + b1.w;
  if (OBF) {
    v8u pk = { f2bf(o0), f2bf(o1), f2bf(o2), f2bf(o3), f2bf(o4), f2bf(o5), f2bf(o6), f2bf(o7) };
    *(v8u*)((u16*)out + (size_t)row * 512 + lane * 8) = pk;
  } else {
    float4* op = (float4*)((float*)out + (size_t)row * 512);
    op[lane * 2] = make_float4(o0, o1, o2, o3);
    op[lane * 2 + 1] = make_float4(o4, o5, o6, o7);
  }
}

// ---------- GEMM 128x128, BK=64, XOR-swizzled LDS ----------
// C = A(MxK,bf16) * BT(NxK,bf16)^T + bias [+gelu] [+resid]
template<int ACT, int RESID, int OBF>
__global__ __launch_bounds__(256) void gemm_bt(
    const u16* __restrict__ A, const u16* __restrict__ BT,
    const float* __restrict__ bias, const float* __restrict__ resid,
    void* __restrict__ Cout, int N, int K)
{
  __shared__ u16 As[128 * 64];
  __shared__ u16 Bs[128 * 64];
  const int m0 = blockIdx.y * 128, n0 = blockIdx.x * 128;
  const int t = threadIdx.x, lane = t & 63, w = t >> 6;
  const int lr = lane & 15, lq = lane >> 4;
  const int wm = (w & 1) * 64, wn = (w >> 1) * 64;
  v4f acc[4][4];
  const v4f vzero = {0.f, 0.f, 0.f, 0.f};
#pragma unroll
  for (int mt = 0; mt < 4; ++mt)
#pragma unroll
    for (int nt = 0; nt < 4; ++nt) acc[mt][nt] = vzero;

  // staging chunk map: chunk c (0..1023) -> row=c>>3, global 16B-chunk gs=(c&7)^(row&7)
  int srow[4], sgs[4];
#pragma unroll
  for (int i = 0; i < 4; ++i) {
    int c = t + i * 256;
    srow[i] = c >> 3;
    sgs[i] = (c & 7) ^ (srow[i] & 7);
  }

  for (int kk = 0; kk < K; kk += 64) {
    __syncthreads();
#pragma unroll
    for (int i = 0; i < 4; ++i) {
      gl_lds16(A  + (size_t)(m0 + srow[i]) * K + kk + sgs[i] * 8, As + (size_t)(w * 64 + i * 256) * 8);
      gl_lds16(BT + (size_t)(n0 + srow[i]) * K + kk + sgs[i] * 8, Bs + (size_t)(w * 64 + i * 256) * 8);
    }
    __syncthreads();
#pragma unroll
    for (int ks = 0; ks < 2; ++ks) {
      v8s a[4], b[4];
#pragma unroll
      for (int mt = 0; mt < 4; ++mt) {
        int row = wm + mt * 16 + lr;
        int cL = (ks * 4 + lq) ^ (row & 7);
        a[mt] = *(const v8s*)(As + row * 64 + cL * 8);
      }
#pragma unroll
      for (int nt = 0; nt < 4; ++nt) {
        int row = wn + nt * 16 + lr;
        int cL = (ks * 4 + lq) ^ (row & 7);
        b[nt] = *(const v8s*)(Bs + row * 64 + cL * 8);
      }
#pragma unroll
      for (int mt = 0; mt < 4; ++mt)
#pragma unroll
        for (int nt = 0; nt < 4; ++nt)
          acc[mt][nt] = mfma16(a[mt], b[nt], acc[mt][nt]);
    }
  }

#pragma unroll
  for (int mt = 0; mt < 4; ++mt)
#pragma unroll
    for (int nt = 0; nt < 4; ++nt) {
      int col = n0 + wn + nt * 16 + lr;
      float bsv = bias[col];
#pragma unroll
      for (int r = 0; r < 4; ++r) {
        int row = m0 + wm + mt * 16 + lq * 4 + r;
        float v = acc[mt][nt][r] + bsv;
        if (ACT == 1) v = fast_gelu(v);
        if (RESID) v += resid[(size_t)row * N + col];
        if (OBF) ((u16*)Cout)[(size_t)row * N + col] = f2bf(v);
        else     ((float*)Cout)[(size_t)row * N + col] = v;
      }
    }
}

// ---------- GEMM 128x64 tile, BK=64, swizzled (N=512: 256 blocks) ----------
template<int ACT, int RESID, int OBF>
__global__ __launch_bounds__(256) void gemm_bt64(
    const u16* __restrict__ A, const u16* __restrict__ BT,
    const float* __restrict__ bias, const float* __restrict__ resid,
    void* __restrict__ Cout, int N, int K)
{
  __shared__ u16 As[128 * 64];
  __shared__ u16 Bs[64 * 64];
  const int m0 = blockIdx.y * 128, n0 = blockIdx.x * 64;
  const int t = threadIdx.x, lane = t & 63, w = t >> 6;
  const int lr = lane & 15, lq = lane >> 4;
  const int wm = (w & 1) * 64, wn = (w >> 1) * 32;
  v4f acc[4][2];
  const v4f vzero = {0.f, 0.f, 0.f, 0.f};
#pragma unroll
  for (int mt = 0; mt < 4; ++mt)
#pragma unroll
    for (int nt = 0; nt < 2; ++nt) acc[mt][nt] = vzero;

  int srow[4], sgs[4];
#pragma unroll
  for (int i = 0; i < 4; ++i) {
    int c = t + i * 256;
    srow[i] = c >> 3;
    sgs[i] = (c & 7) ^ (srow[i] & 7);
  }

  for (int kk = 0; kk < K; kk += 64) {
    __syncthreads();
#pragma unroll
    for (int i = 0; i < 4; ++i)
      gl_lds16(A + (size_t)(m0 + srow[i]) * K + kk + sgs[i] * 8, As + (size_t)(w * 64 + i * 256) * 8);
#pragma unroll
    for (int i = 0; i < 2; ++i)
      gl_lds16(BT + (size_t)(n0 + srow[i]) * K + kk + sgs[i] * 8, Bs + (size_t)(w * 64 + i * 256) * 8);
    __syncthreads();
#pragma unroll
    for (int ks = 0; ks < 2; ++ks) {
      v8s a[4], b[2];
#pragma unroll
      for (int mt = 0; mt < 4; ++mt) {
        int row = wm + mt * 16 + lr;
        int cL = (ks * 4 + lq) ^ (row & 7);
        a[mt] = *(const v8s*)(As + row * 64 + cL * 8);
      }
#pragma unroll
      for (int nt = 0; nt < 2; ++nt) {
        int row = wn + nt * 16 + lr;
        int cL = (ks * 4 + lq) ^ (row & 7);
        b[nt] = *(const v8s*)(Bs + row * 64 + cL * 8);
      }
#pragma unroll
      for (int mt = 0; mt < 4; ++mt)
#pragma unroll
        for (int nt = 0; nt < 2; ++nt)
          acc[mt][nt] = mfma16(a[mt], b[nt], acc[mt][nt]);
    }
  }

#pragma unroll
  for (int mt = 0; mt < 4; ++mt)
#pragma unroll
    for (int nt = 0; nt < 2; ++nt) {
      int col = n0 + wn + nt * 16 + lr;
      float bsv = bias[col];
#pragma unroll
      for (int r = 0; r < 4; ++r) {
        int row = m0 + wm + mt * 16 + lq * 4 + r;
        float v = acc[mt][nt][r] + bsv;
        if (ACT == 1) v = fast_gelu(v);
        if (RESID) v += resid[(size_t)row * N + col];
        if (OBF) ((u16*)Cout)[(size_t)row * N + col] = f2bf(v);
        else     ((float*)Cout)[(size_t)row * N + col] = v;
      }
    }
}

// ---------- fused attention: one block per (b,h) ----------
__global__ __launch_bounds__(256) void attn_kernel(
    const u16* __restrict__ qkv, u16* __restrict__ attn_out)
{
  __shared__ u16 Ks[128 * 64];
  __shared__ u16 Vt[64 * 128];
  __shared__ u16 Ps[128 * 128];
  const int h = blockIdx.x, b = blockIdx.y;
  const int t = threadIdx.x, lane = t & 63, w = t >> 6;
  const int lr = lane & 15, lq = lane >> 4;
  const u16* base = qkv + (size_t)b * 128 * 1536 + h * 64;

#pragma unroll
  for (int i = 0; i < 4; ++i) {
    int ch = i * 256 + t;            // 0..1023
    int s = ch >> 3, off = (ch & 7) * 8;
    *(v8s*)(Ks + s * 64 + off) = *(const v8s*)(base + 512 + (size_t)s * 1536 + off);
    v8s vv = *(const v8s*)(base + 1024 + (size_t)s * 1536 + off);
#pragma unroll
    for (int j = 0; j < 8; ++j) Vt[(off + j) * 128 + s] = (u16)vv[j];
  }
  __syncthreads();

  const v4f vzero = {0.f, 0.f, 0.f, 0.f};
  v4f sacc[2][8];
#pragma unroll
  for (int mt = 0; mt < 2; ++mt)
#pragma unroll
    for (int nt = 0; nt < 8; ++nt) sacc[mt][nt] = vzero;
#pragma unroll
  for (int kk = 0; kk < 64; kk += 32) {
    v8s a0 = *(const v8s*)(base + (size_t)(w * 32 + lr) * 1536 + kk + lq * 8);
    v8s a1 = *(const v8s*)(base + (size_t)(w * 32 + 16 + lr) * 1536 + kk + lq * 8);
#pragma unroll
    for (int nt = 0; nt < 8; ++nt) {
      v8s bb = *(const v8s*)(Ks + (nt * 16 + lr) * 64 + kk + lq * 8);
      sacc[0][nt] = mfma16(a0, bb, sacc[0][nt]);
      sacc[1][nt] = mfma16(a1, bb, sacc[1][nt]);
    }
  }

  float rinv[2][4];
#pragma unroll
  for (int mt = 0; mt < 2; ++mt)
#pragma unroll
    for (int r = 0; r < 4; ++r) {
      float mx = -3.0e38f;
#pragma unroll
      for (int nt = 0; nt < 8; ++nt) mx = fmaxf(mx, sacc[mt][nt][r]);
#pragma unroll
      for (int d = 1; d < 16; d <<= 1) mx = fmaxf(mx, __shfl_xor(mx, d, 64));
      float ls = 0.f;
      float pv[8];
#pragma unroll
      for (int nt = 0; nt < 8; ++nt) {
        pv[nt] = expf((sacc[mt][nt][r] - mx) * 0.125f);
        ls += pv[nt];
      }
#pragma unroll
      for (int d = 1; d < 16; d <<= 1) ls += __shfl_xor(ls, d, 64);
      rinv[mt][r] = 1.0f / ls;
      int row = w * 32 + mt * 16 + lq * 4 + r;
#pragma unroll
      for (int nt = 0; nt < 8; ++nt) Ps[row * 128 + nt * 16 + lr] = f2bf(pv[nt]);
    }
  __syncthreads();

  v4f oacc[2][4];
#pragma unroll
  for (int mt = 0; mt < 2; ++mt)
#pragma unroll
    for (int nt = 0; nt < 4; ++nt) oacc[mt][nt] = vzero;
#pragma unroll
  for (int kk = 0; kk < 128; kk += 32) {
    v8s a0 = *(const v8s*)(Ps + (w * 32 + lr) * 128 + kk + lq * 8);
    v8s a1 = *(const v8s*)(Ps + (w * 32 + 16 + lr) * 128 + kk + lq * 8);
#pragma unroll
    for (int nt = 0; nt < 4; ++nt) {
      v8s bb = *(const v8s*)(Vt + (nt * 16 + lr) * 128 + kk + lq * 8);
      oacc[0][nt] = mfma16(a0, bb, oacc[0][nt]);
      oacc[1][nt] = mfma16(a1, bb, oacc[1][nt]);
    }
  }
#pragma unroll
  for (int mt = 0; mt < 2; ++mt)
#pragma unroll
    for (int nt = 0; nt < 4; ++nt)
#pragma unroll
      for (int r = 0; r < 4; ++r) {
        int row = w * 32 + mt * 16 + lq * 4 + r;
        int col = nt * 16 + lr;
        attn_out[((size_t)(b * 128 + row)) * 512 + h * 64 + col] =
            f2bf(oacc[mt][nt][r] * rinv[mt][r]);
      }
}

// ---------- bilinear 8x8 -> 32x32 ----------
__global__ __launch_bounds__(256) void upsample_kernel(
    const float* __restrict__ xf, float* __restrict__ out)
{
  int bid = blockIdx.x;               // ((timg*32+b)*512+c)
  int c = bid & 511;
  int tb = bid >> 9;
  int b = tb & 31, timg = tb >> 5;
  __shared__ float tile[64];
  if (threadIdx.x < 64) {
    int s = timg * 64 + threadIdx.x;
    tile[threadIdx.x] = xf[((size_t)b * 128 + s) * 512 + c];
  }
  __syncthreads();
  float* obase = out + (size_t)timg * (32ull * 512 * 1024) + ((size_t)b * 512 + c) * 1024;
#pragma unroll
  for (int k = 0; k < 4; ++k) {
    int pix = threadIdx.x + k * 256;
    int i = pix >> 5, j = pix & 31;
    float cy = fminf(fmaxf((i - 1.5f) * 0.25f, 0.f), 7.f);
    float cx = fminf(fmaxf((j - 1.5f) * 0.25f, 0.f), 7.f);
    int y0 = (int)cy, x0 = (int)cx;
    int y1 = min(y0 + 1, 7), x1 = min(x0 + 1, 7);
    float fy = cy - y0, fx = cx - x0;
    float v00 = tile[y0 * 8 + x0], v01 = tile[y0 * 8 + x1];
    float v10 = tile[y1 * 8 + x0], v11 = tile[y1 * 8 + x1];
    obase[pix] = (v00 * (1.f - fx) + v01 * fx) * (1.f - fy) + (v10 * (1.f - fx) + v11 * fx) * fy;
  }
}

// ---------- host ----------
extern "C" void kernel_launch(void* const* d_in, const int* in_sizes, int n_in,
                              void* d_out, int out_size, void* d_ws, size_t ws_size,
                              hipStream_t stream)
{
  const float* rgb_fea = (const float*)d_in[0];
  const float* ir_fea  = (const float*)d_in[1];
  const float* pos_emb = (const float*)d_in[2];
  const float* conv1_w = (const float*)d_in[3];
  const float* conv2_w = (const float*)d_in[4];
  const float* ln1_w = (const float*)d_in[5];
  const float* ln1_b = (const float*)d_in[6];
  const float* Wq = (const float*)d_in[7];
  const float* bq = (const float*)d_in[8];
  const float* Wk = (const float*)d_in[9];
  const float* bk = (const float*)d_in[10];
  const float* Wv = (const float*)d_in[11];
  const float* bv = (const float*)d_in[12];
  const float* Wo = (const float*)d_in[13];
  const float* bo = (const float*)d_in[14];
  const float* ln2_w = (const float*)d_in[15];
  const float* ln2_b = (const float*)d_in[16];
  const float* W1 = (const float*)d_in[17];
  const float* b1 = (const float*)d_in[18];
  const float* W2 = (const float*)d_in[19];
  const float* b2 = (const float*)d_in[20];
  const float* lnf_w = (const float*)d_in[21];
  const float* lnf_b = (const float*)d_in[22];
  (void)in_sizes; (void)n_in; (void)out_size; (void)ws_size;

  char* wsb = (char*)d_ws;
  size_t off = 0;
  auto alloc = [&](size_t nbytes) -> void* {
    void* p = wsb + off;
    off += (nbytes + 255) & ~(size_t)255;
    return p;
  };
  float* pool   = (float*)alloc(2ull * 32 * 512 * 64 * 4);   // 8 MB
  float* Macc   = (float*)alloc(8ull * 72 * 512 * 4);        // 1.2 MB
  float* Mplain = (float*)alloc(2ull * 32 * 8 * 64 * 4);
  float* Mhp    = (float*)alloc(2ull * 4 * 8 * 64 * 4);
  float* x      = (float*)alloc((size_t)MTOT * 512 * 4);
  float* xf     = (float*)alloc((size_t)MTOT * 512 * 4);
  u16* ln_out   = (u16*)alloc((size_t)MTOT * 512 * 2);
  u16* qkv      = (u16*)alloc((size_t)MTOT * 1536 * 2);
  u16* attn     = (u16*)alloc((size_t)MTOT * 512 * 2);
  u16* hbuf     = (u16*)alloc((size_t)MTOT * 2048 * 2);
  u16* WqkvT    = (u16*)alloc(8ull * 1536 * 512 * 2);
  u16* WoT      = (u16*)alloc(8ull * 512 * 512 * 2);
  u16* W1T      = (u16*)alloc(8ull * 2048 * 512 * 2);
  u16* W2T      = (u16*)alloc(8ull * 512 * 2048 * 2);
  float* qb     = (float*)alloc(8ull * 1536 * 4);

  // weight prep
  qkv_transpose_kernel<<<dim3(16, 16, 24), 256, 0, stream>>>(Wq, Wk, Wv, WqkvT);
  transpose_bf16_kernel<<<dim3(16, 16, 8), 256, 0, stream>>>(Wo, WoT, 512, 512, 512ull * 512, 512ull * 512, 0);
  transpose_bf16_kernel<<<dim3(64, 16, 8), 256, 0, stream>>>(W1, W1T, 512, 2048, 512ull * 2048, 2048ull * 512, 0);
  transpose_bf16_kernel<<<dim3(16, 64, 8), 256, 0, stream>>>(W2, W2T, 2048, 512, 2048ull * 512, 512ull * 2048, 0);
  qkvbias_kernel<<<8, 256, 0, stream>>>(bq, bk, bv, qb);

  // front-end
  pool_kernel<<<8192, 256, 0, stream>>>(rgb_fea, ir_fea, pool);
  convm_kernel<<<dim3(72, 8), 256, 0, stream>>>(pool, conv1_w, Macc);
  msig_kernel<<<144, 256, 0, stream>>>(Macc, Mplain, Mhp);
  loss_kernel<<<1, 256, 0, stream>>>(Mplain, Mhp, (float*)d_out + 33554432);
  token_kernel<<<MTOT, 256, 0, stream>>>(pos_emb, conv2_w, Mplain, pool, x);

  // transformer
  for (int l = 0; l < 8; ++l) {
    ln_kernel<1><<<MTOT / 4, 256, 0, stream>>>(x, ln1_w + l * 512, ln1_b + l * 512, ln_out);
    gemm_bt<0, 0, 1><<<dim3(12, 32), 256, 0, stream>>>(
        ln_out, WqkvT + (size_t)l * 1536 * 512, qb + l * 1536, nullptr, qkv, 1536, 512);
    attn_kernel<<<dim3(8, 32), 256, 0, stream>>>(qkv, attn);
    gemm_bt64<0, 1, 0><<<dim3(8, 32), 256, 0, stream>>>(
        attn, WoT + (size_t)l * 512 * 512, bo + l * 512, x, x, 512, 512);
    ln_kernel<1><<<MTOT / 4, 256, 0, stream>>>(x, ln2_w + l * 512, ln2_b + l * 512, ln_out);
    gemm_bt<1, 0, 1><<<dim3(16, 32), 256, 0, stream>>>(
        ln_out, W1T + (size_t)l * 2048 * 512, b1 + l * 2048, nullptr, hbuf, 2048, 512);
    gemm_bt64<0, 1, 0><<<dim3(8, 32), 256, 0, stream>>>(
        hbuf, W2T + (size_t)l * 512 * 2048, b2 + l * 512, x, x, 512, 2048);
  }

  // final LN + upsample
  ln_kernel<0><<<MTOT / 4, 256, 0, stream>>>(x, lnf_w, lnf_b, xf);
  upsample_kernel<<<32768, 256, 0, stream>>>(xf, (float*)d_out);
}